// Round 11
// baseline (140.962 us; speedup 1.0000x reference)
//
#include <hip/hip_runtime.h>
#include <hip/hip_bf16.h>

typedef __bf16 bf16;
typedef __bf16 bf16x2 __attribute__((ext_vector_type(2)));
typedef __bf16 bf16x4 __attribute__((ext_vector_type(4)));
typedef __bf16 bf16x8 __attribute__((ext_vector_type(8)));
typedef float f32x4 __attribute__((ext_vector_type(4)));
typedef int i32x4 __attribute__((ext_vector_type(4)));

#define B_ 8
#define N_ 1024
#define C_ 256
#define H_ 8
#define C3_ 768
#define SCALE 0.17677669529663689f  // 1/sqrt(32), pre-folded into q
#define FMAX 16.0f                  // fixed softmax max, pre-folded into ebtl

// ws layout:
//   Wp_tiled [8 kt][256 n][32 k]         131072 B  @ 393216
//   q  [8192][256] (pre-scaled by SCALE) 4 MiB     @ 524288
//   kT [b][h][1024 n][32 d]              4 MiB     @ 4718592
//   vT [b][c=h*32+d][1024 n']            4 MiB     @ 8912896
//   rel8 [b][i][j] int8                  8 MiB     @ 13107200
// vT perm (matches swapped-QK P fragment, k-slot = quad*8+e):
//   n' = (n&~31) | ((n&12)<<1) | (n&3) | (((n>>4)&1)<<2)

// ---------------------------------------------------------------------------
// Fused producer kernel (R10-frozen):
//   blocks 0..767    : 64x128 QKV gemm tiles, B staged directly from raw
//                      Wqkv (in-kernel transpose, XOR-chunk swizzle).
//   blocks 768..2815 : rel int32 -> int8 pack.
//   blocks 2816..3071: Wproj tiling.
// ---------------------------------------------------------------------------
__global__ __launch_bounds__(256) void gemm_qkv(
    const float* __restrict__ A, const float* __restrict__ Wqkv,
    const float* __restrict__ Wproj, const int* __restrict__ rel,
    bf16* __restrict__ q, bf16* __restrict__ kT, bf16* __restrict__ vT,
    bf16* __restrict__ Wp_tiled, unsigned char* __restrict__ rel8)
{
  __shared__ __align__(16) char sm[18432];

  int bb = blockIdx.x;
  int tid = threadIdx.x;

  if (bb >= 768) {
    if (bb < 2816) {
      // rel pack: 2048 blocks x 256 thr x 16 elems
      long p = ((long)(bb - 768) * 256 + tid) * 16;
      i32x4 a = *reinterpret_cast<const i32x4*>(rel + p);
      i32x4 b2 = *reinterpret_cast<const i32x4*>(rel + p + 4);
      i32x4 c = *reinterpret_cast<const i32x4*>(rel + p + 8);
      i32x4 d = *reinterpret_cast<const i32x4*>(rel + p + 12);
      unsigned o0 = (unsigned)a[0] | ((unsigned)a[1] << 8) | ((unsigned)a[2] << 16) | ((unsigned)a[3] << 24);
      unsigned o1 = (unsigned)b2[0] | ((unsigned)b2[1] << 8) | ((unsigned)b2[2] << 16) | ((unsigned)b2[3] << 24);
      unsigned o2 = (unsigned)c[0] | ((unsigned)c[1] << 8) | ((unsigned)c[2] << 16) | ((unsigned)c[3] << 24);
      unsigned o3 = (unsigned)d[0] | ((unsigned)d[1] << 8) | ((unsigned)d[2] << 16) | ((unsigned)d[3] << 24);
      i32x4 ov = {(int)o0, (int)o1, (int)o2, (int)o3};
      *reinterpret_cast<i32x4*>(rel8 + p) = ov;
    } else {
      int p = (bb - 2816) * 256 + tid;
      int kk = p & 31;
      int n = (p >> 5) & 255;
      int kt = p >> 13;
      Wp_tiled[p] = (bf16)Wproj[(kt * 32 + kk) * C_ + n];
    }
    return;
  }

  bf16 (*As)[40] = (bf16(*)[40])(void*)sm;            // [64][40]
  bf16 (*Bs)[40] = (bf16(*)[40])(void*)(sm + 5120);   // [128 n][40] (swizzled k)

  int wave = tid >> 6, lane = tid & 63, quad = lane >> 4, l16 = lane & 15;
  int x = bb & 127, y = bb >> 7;          // m-tile (64 rows), n-tile (128 cols)
  int m0 = x * 64, n0 = y * 128;
  int msub = (wave & 1) * 32, nsub = (wave >> 1) * 64;

  f32x4 acc[2][4] = {};

  int arow = tid >> 2, akc = (tid & 3) * 8;
  const float* aptr = A + (long)(m0 + arow) * C_ + akc;   // + kt*32

  int bk = tid >> 3, bns = (tid & 7) * 16;
  int bcp = (((bk >> 3) ^ (tid & 3)) << 3) + (bk & 7);
  const float* wq = Wqkv + (long)bk * C3_ + n0 + bns;     // + kt*32*C3_

  float4 a0 = *reinterpret_cast<const float4*>(aptr);
  float4 a1 = *reinterpret_cast<const float4*>(aptr + 4);
  float4 f0 = *reinterpret_cast<const float4*>(wq);
  float4 f1 = *reinterpret_cast<const float4*>(wq + 4);
  float4 f2 = *reinterpret_cast<const float4*>(wq + 8);
  float4 f3 = *reinterpret_cast<const float4*>(wq + 12);

  for (int kt = 0; kt < 8; ++kt) {
    __syncthreads();
    {
      bf16 at[8] = {(bf16)a0.x, (bf16)a0.y, (bf16)a0.z, (bf16)a0.w,
                    (bf16)a1.x, (bf16)a1.y, (bf16)a1.z, (bf16)a1.w};
      *reinterpret_cast<bf16x8*>(&As[arow][akc]) = *reinterpret_cast<bf16x8*>(at);
      float vv[16] = {f0.x, f0.y, f0.z, f0.w, f1.x, f1.y, f1.z, f1.w,
                      f2.x, f2.y, f2.z, f2.w, f3.x, f3.y, f3.z, f3.w};
#pragma unroll
      for (int i = 0; i < 16; ++i)
        Bs[bns + i][bcp] = (bf16)vv[i];
    }
    __syncthreads();

    if (kt < 7) {
      int kn = (kt + 1) * 32;
      a0 = *reinterpret_cast<const float4*>(aptr + kn);
      a1 = *reinterpret_cast<const float4*>(aptr + kn + 4);
      const float* wqn = wq + (long)kn * C3_;
      f0 = *reinterpret_cast<const float4*>(wqn);
      f1 = *reinterpret_cast<const float4*>(wqn + 4);
      f2 = *reinterpret_cast<const float4*>(wqn + 8);
      f3 = *reinterpret_cast<const float4*>(wqn + 12);
    }

    bf16x8 af[2], bfr[4];
#pragma unroll
    for (int mi = 0; mi < 2; ++mi)
      af[mi] = *reinterpret_cast<const bf16x8*>(&As[msub + mi * 16 + l16][quad * 8]);
#pragma unroll
    for (int ni = 0; ni < 4; ++ni)
      bfr[ni] = *reinterpret_cast<const bf16x8*>(
          &Bs[nsub + ni * 16 + l16][(quad ^ ni) << 3]);
#pragma unroll
    for (int mi = 0; mi < 2; ++mi)
#pragma unroll
      for (int ni = 0; ni < 4; ++ni)
        acc[mi][ni] = __builtin_amdgcn_mfma_f32_16x16x32_bf16(af[mi], bfr[ni], acc[mi][ni], 0, 0, 0);
  }

  __syncthreads();  // all frag reads done; reuse sm for epilogue staging

  if (y < 4) {
    float mul = (y < 2) ? SCALE : 1.0f;
    bf16 (*Ep)[136] = (bf16(*)[136])(void*)sm;
#pragma unroll
    for (int mi = 0; mi < 2; ++mi)
#pragma unroll
      for (int ni = 0; ni < 4; ++ni)
#pragma unroll
        for (int r = 0; r < 4; ++r)
          Ep[msub + mi * 16 + quad * 4 + r][nsub + ni * 16 + l16] =
              (bf16)(acc[mi][ni][r] * mul);
    __syncthreads();
    int row = tid >> 2, seg = tid & 3;
    i32x4 w0 = *reinterpret_cast<const i32x4*>(&Ep[row][seg * 32]);
    i32x4 w1 = *reinterpret_cast<const i32x4*>(&Ep[row][seg * 32 + 8]);
    i32x4 w2 = *reinterpret_cast<const i32x4*>(&Ep[row][seg * 32 + 16]);
    i32x4 w3 = *reinterpret_cast<const i32x4*>(&Ep[row][seg * 32 + 24]);
    bf16* dst;
    if (y < 2) {
      dst = q + (long)(m0 + row) * 256 + n0 + seg * 32;
    } else {
      int c = n0 - 256 + seg * 32;       // multiple of 32 -> exactly one h
      int h = c >> 5;
      int gr = m0 + row, b = gr >> 10, n = gr & 1023;
      dst = kT + (((long)(b * H_ + h)) * N_ + n) * 32;
    }
    *reinterpret_cast<i32x4*>(dst) = w0;
    *reinterpret_cast<i32x4*>(dst + 8) = w1;
    *reinterpret_cast<i32x4*>(dst + 16) = w2;
    *reinterpret_cast<i32x4*>(dst + 24) = w3;
  } else {
    bf16 (*Vls)[72] = (bf16(*)[72])(void*)sm;
#pragma unroll
    for (int mi = 0; mi < 2; ++mi)
#pragma unroll
      for (int ni = 0; ni < 4; ++ni)
#pragma unroll
        for (int r = 0; r < 4; ++r) {
          int nn = msub + mi * 16 + quad * 4 + r;   // 0..63
          int np = (nn & ~31) | ((nn & 12) << 1) | (nn & 3) | (((nn >> 4) & 1) << 2);
          Vls[nsub + ni * 16 + l16][np] = (bf16)acc[mi][ni][r];
        }
    __syncthreads();
    int c = tid >> 1, nseg = (tid & 1) * 32;
    i32x4 w0 = *reinterpret_cast<const i32x4*>(&Vls[c][nseg]);
    i32x4 w1 = *reinterpret_cast<const i32x4*>(&Vls[c][nseg + 8]);
    i32x4 w2 = *reinterpret_cast<const i32x4*>(&Vls[c][nseg + 16]);
    i32x4 w3 = *reinterpret_cast<const i32x4*>(&Vls[c][nseg + 24]);
    int gb = m0 >> 10, mn = m0 & 1023;
    bf16* dst = vT + ((long)(gb * C_ + (n0 - 512) + c)) * N_ + mn + nseg;
    *reinterpret_cast<i32x4*>(dst) = w0;
    *reinterpret_cast<i32x4*>(dst + 8) = w1;
    *reinterpret_cast<i32x4*>(dst + 16) = w2;
    *reinterpret_cast<i32x4*>(dst + 24) = w3;
  }
}

// ---------------------------------------------------------------------------
// Flash attention + fused projection — R8 structure with rel8 DOUBLE-buffer:
// LDS 78336 -> 74240 B restores 2 blocks/CU (R5-proven size; R6/R8's 78336
// ran 1 block/CU per occupancy counters). Schedule per tile T (all wave-
// private, barrier-free): issue KV(T+1)->KB/VB((T+1)&1), rel8(T+2)->RB(T&1);
// vmcnt(6) = only this tile's 6 issues outstanding (everything older
// arrived); read KV(T), read-ahead rel8(T+1) from RB((T+1)&1). WAR ordering
// is isomorphic to the replay-proven KV double-buffer. Prologue is the R8
// order-proof full drain (R7's race suspect was its vmcnt(2) prologue).
// ---------------------------------------------------------------------------
__global__ __launch_bounds__(512) void flash_attn(
    const bf16* __restrict__ q, const bf16* __restrict__ kT,
    const bf16* __restrict__ vT, const unsigned char* __restrict__ rel8,
    const int* __restrict__ rel_len, const float* __restrict__ btab,
    const bf16* __restrict__ Wp_tiled, const float* __restrict__ bias,
    float* __restrict__ out)
{
  __shared__ __align__(16) char smem[74240];
  char* const KB0 = smem;            // [2][8][2048]
  char* const VB0 = smem + 32768;    // [2][8][2048]
  char* const RB0 = smem + 65536;    // [2][8][512]
  float* const ebtl = (float*)(smem + 73728);  // [8][16]

  int tid = threadIdx.x;
  int h = tid >> 6, lane = tid & 63, quad = lane >> 4, l16 = lane & 15;

  // bijective XCD swizzle (512 blocks = 8 XCDs x 64): XCD k -> batch k.
  int wg = blockIdx.y * 64 + blockIdx.x;
  int swz = (wg & 7) * 64 + (wg >> 3);
  int b = swz >> 6, i0 = (swz & 63) * 16;
  long bN = (long)b * N_;

  int mask_len = (int)((float)rel_len[b] * 0.5f);
  if (tid < 80) {
    int t = tid >> 3, hh = tid & 7;
    ebtl[hh * 16 + t] = __expf(btab[t * H_ + hh] + (t > mask_len ? -100.f : 0.f) - FMAX);
  }

  // Q as B-fragment: col = q-row (l16), k = d (quad*8+e)
  bf16x8 qf = *reinterpret_cast<const bf16x8*>(
      q + (bN + i0 + l16) * 256 + h * 32 + quad * 8);

  // ebtl visible + prologue VMEM drained so loop vmcnt counts only DMAs.
  __syncthreads();

  // ---- per-lane DMA source offsets (16B-slot swizzle pre-applied) ----
  int l = lane;
  int sxc = (((l & 3) ^ ((l >> 3) & 3)) << 4);
  int kc0 = (l >> 2) * 64 + sxc;                  // K: row l>>2, 2nd GLD +1024
  int vc0 = (h * 32 + (l >> 2)) * 2048 + sxc;     // V: chan h*32+(l>>2), 2nd +32768
  int rc0 = (l >> 3) * 1024 + (l & 7) * 4;        // rel8: row l>>3, 2nd GLD +8192

  const char* kTb = (const char*)kT + ((long)(b * 8 + h) << 16);  // +t*2048
  const char* vTb = (const char*)vT + (long)b * 524288;           // +t*64
  const char* rb8 = (const char*)rel8 + (bN + i0) * 1024;         // +t*32

  // ---- LDS read offsets ----
  int swq = ((quad ^ ((l16 >> 1) & 3)) << 4);
  int kr = h * 2048 + l16 * 64 + swq;      // K/V: row l16 (+1024: row 16+l16)
  int rr = h * 512 + l16 * 32 + quad * 4;  // rel8: row l16, j=4q (+16: j=16+4q)

#define KB(i) (KB0 + (i) * 16384)
#define VB(i) (VB0 + (i) * 16384)
#define RB(i) (RB0 + (i) * 4096)

#define GLD16(G, L) __builtin_amdgcn_global_load_lds(                         \
    (const __attribute__((address_space(1))) void*)(G),                       \
    (__attribute__((address_space(3))) void*)(L), 16, 0, 0)
#define GLD4(G, L) __builtin_amdgcn_global_load_lds(                          \
    (const __attribute__((address_space(1))) void*)(G),                       \
    (__attribute__((address_space(3))) void*)(L), 4, 0, 0)

#define GATH(G, RV0, RV1) do {                                                \
    _Pragma("unroll")                                                         \
    for (int e = 0; e < 4; ++e) {                                             \
      G[e]     = ebtl[h * 16 + (int)((RV0 >> (8 * e)) & 255u)];               \
      G[4 + e] = ebtl[h * 16 + (int)((RV1 >> (8 * e)) & 255u)];               \
    }                                                                         \
  } while (0)

#define COMP(K0, K1, V0, V1, G) do {                                          \
    f32x4 z = {};                                                             \
    f32x4 s0 = __builtin_amdgcn_mfma_f32_16x16x32_bf16(K0, qf, z, 0, 0, 0);   \
    f32x4 s1 = __builtin_amdgcn_mfma_f32_16x16x32_bf16(K1, qf, z, 0, 0, 0);   \
    bf16x8 pa;                                                                \
    _Pragma("unroll")                                                         \
    for (int e = 0; e < 4; ++e) {                                             \
      float p0 = __expf(s0[e]) * G[e];                                        \
      float p1 = __expf(s1[e]) * G[4 + e];                                    \
      l_acc += p0 + p1;                                                       \
      pa[e] = (bf16)p0;                                                       \
      pa[4 + e] = (bf16)p1;                                                   \
    }                                                                         \
    oacc[0] = __builtin_amdgcn_mfma_f32_16x16x32_bf16(pa, V0, oacc[0], 0, 0, 0); \
    oacc[1] = __builtin_amdgcn_mfma_f32_16x16x32_bf16(pa, V1, oacc[1], 0, 0, 0); \
  } while (0)

// Tile T (KVR=T&1, KVW=(T+1)&1): issue KV(T+1)->KB/VB(KVW), rel8(T+2)->
// RB(KVR); vmcnt(6) leaves only this tile's 6 issues outstanding -> KV(T)
// and rel8(T+1) (issued at T-1) have arrived; read KV(T) from KVR, read-
// ahead rel8(T+1) from RB(KVW); gather GN for T+1; compute T with GC.
// WAR: RB(KVR) was read at T-1 (program order precedes this issue) — same
// proven pattern as KB/VB. No barriers.
#define TILE(T_, KVR, KVW, GC, GN) do {                                       \
    int tn_ = ((T_) + 1) & 31, tr_ = ((T_) + 2) & 31;                         \
    GLD16(kTb + tn_ * 2048 + kc0,        KB(KVW) + h * 2048);                 \
    GLD16(kTb + tn_ * 2048 + kc0 + 1024, KB(KVW) + h * 2048 + 1024);          \
    GLD16(vTb + tn_ * 64 + vc0,          VB(KVW) + h * 2048);                 \
    GLD16(vTb + tn_ * 64 + vc0 + 32768,  VB(KVW) + h * 2048 + 1024);          \
    GLD4(rb8 + tr_ * 32 + rc0,           RB(KVR) + h * 512);                  \
    GLD4(rb8 + tr_ * 32 + rc0 + 8192,    RB(KVR) + h * 512 + 256);            \
    asm volatile("s_waitcnt vmcnt(6)" ::: "memory");                          \
    bf16x8 kf0 = *(const bf16x8*)(KB(KVR) + kr);                              \
    bf16x8 kf1 = *(const bf16x8*)(KB(KVR) + kr + 1024);                       \
    bf16x8 vf0 = *(const bf16x8*)(VB(KVR) + kr);                              \
    bf16x8 vf1 = *(const bf16x8*)(VB(KVR) + kr + 1024);                       \
    unsigned rv0 = *(const unsigned*)(RB(KVW) + rr);                          \
    unsigned rv1 = *(const unsigned*)(RB(KVW) + rr + 16);                     \
    GATH(GN, rv0, rv1);                                                       \
    COMP(kf0, kf1, vf0, vf1, GC);                                             \
  } while (0)

  f32x4 oacc[2] = {};
  float l_acc = 0.f;
  float gA[8], gB[8];

  // ---- prologue: KV(0)->buf0; rel8(0)->RB(0), rel8(1)->RB(1); full drain
  // (order-proof — R7's vmcnt(2) here was the race suspect); gather gA(0).
  GLD16(kTb + kc0,        KB(0) + h * 2048);
  GLD16(kTb + kc0 + 1024, KB(0) + h * 2048 + 1024);
  GLD16(vTb + vc0,          VB(0) + h * 2048);
  GLD16(vTb + vc0 + 32768,  VB(0) + h * 2048 + 1024);
  GLD4(rb8 + rc0,             RB(0) + h * 512);
  GLD4(rb8 + rc0 + 8192,      RB(0) + h * 512 + 256);
  GLD4(rb8 + 32 + rc0,        RB(1) + h * 512);
  GLD4(rb8 + 32 + rc0 + 8192, RB(1) + h * 512 + 256);
  asm volatile("s_waitcnt vmcnt(0)" ::: "memory");
  {
    unsigned rv0 = *(const unsigned*)(RB(0) + rr);
    unsigned rv1 = *(const unsigned*)(RB(0) + rr + 16);
    GATH(gA, rv0, rv1);
  }
  // t=0 writes rel8(2) into RB(0): gA was gathered above, before that issue
  // in program order — read-before-overwrite holds.

#pragma unroll 1
  for (int t = 0; t < 32; t += 2) {
    TILE(t + 0, 0, 1, gA, gB);
    TILE(t + 1, 1, 0, gB, gA);
  }
#undef TILE
#undef COMP
#undef GATH
#undef GLD16
#undef GLD4
#undef KB
#undef VB
#undef RB

  // drain wrapped tail DMAs before aliasing smem as attL
  asm volatile("s_waitcnt vmcnt(0)" ::: "memory");
  __syncthreads();

  // row sums: lane's p's are all for q-row l16 -> reduce across quads.
  float lsum = l_acc;
  lsum += __shfl_xor(lsum, 16);
  lsum += __shfl_xor(lsum, 32);
  float inv = 1.f / lsum;   // inv for q-row = l16

  bf16 (*attL)[264] = (bf16(*)[264])(void*)smem;
#pragma unroll
  for (int r = 0; r < 4; ++r) {
    float invr = __shfl(inv, quad * 4 + r);
    attL[quad * 4 + r][h * 32 + l16] = (bf16)(oacc[0][r] * invr);
    attL[quad * 4 + r][h * 32 + 16 + l16] = (bf16)(oacc[1][r] * invr);
  }
  __syncthreads();

  // fused projection: wave h computes out[16 rows][h*32 .. h*32+31]
  f32x4 pacc[2] = {};
  const bf16* wp = Wp_tiled + ((h * 32 + l16) * 32 + quad * 8);  // + kt*8192, +512 for ni=1
#pragma unroll
  for (int kt = 0; kt < 8; ++kt) {
    bf16x8 afr = *reinterpret_cast<const bf16x8*>(&attL[l16][kt * 32 + quad * 8]);
    bf16x8 b0 = *reinterpret_cast<const bf16x8*>(wp + kt * 8192);
    bf16x8 b1 = *reinterpret_cast<const bf16x8*>(wp + kt * 8192 + 512);
    pacc[0] = __builtin_amdgcn_mfma_f32_16x16x32_bf16(afr, b0, pacc[0], 0, 0, 0);
    pacc[1] = __builtin_amdgcn_mfma_f32_16x16x32_bf16(afr, b1, pacc[1], 0, 0, 0);
  }
  float bi0 = bias[h * 32 + l16];
  float bi1 = bias[h * 32 + 16 + l16];
#pragma unroll
  for (int r = 0; r < 4; ++r) {
    long rowoff = (bN + i0 + quad * 4 + r) * C_ + h * 32;
    out[rowoff + l16] = pacc[0][r] + bi0;
    out[rowoff + 16 + l16] = pacc[1][r] + bi1;
  }
}

// ---------------------------------------------------------------------------
extern "C" void kernel_launch(void* const* d_in, const int* in_sizes, int n_in,
                              void* d_out, int out_size, void* d_ws, size_t ws_size,
                              hipStream_t stream) {
  const float* X     = (const float*)d_in[0];   // att_embedding [8,1024,256] fp32
  const int*   rel   = (const int*)d_in[1];     // relation_position [8,1024,1024]
  const int*   rlen  = (const int*)d_in[2];     // rel_len [8]
  const float* Wqkv  = (const float*)d_in[3];   // [256,768] fp32
  const float* Wproj = (const float*)d_in[4];   // [256,256] fp32
  const float* bproj = (const float*)d_in[5];   // [256] fp32
  const float* btab  = (const float*)d_in[6];   // [10,8] fp32
  float* out = (float*)d_out;                   // [8,1024,256] fp32

  char* ws = (char*)d_ws;
  bf16* Wp_tiled = (bf16*)(ws + 393216);                 // 131072 B
  bf16* q  = (bf16*)(ws + 524288);                       // 4 MiB
  bf16* kT = (bf16*)(ws + 524288 + 4194304);             // 4 MiB
  bf16* vT = (bf16*)(ws + 524288 + 2 * 4194304);         // 4 MiB
  unsigned char* rel8 = (unsigned char*)(ws + 13107200); // 8 MiB

  gemm_qkv<<<dim3(3072), 256, 0, stream>>>(X, Wqkv, Wproj, rel,
                                           q, kT, vT, Wp_tiled, rel8);
  flash_attn<<<dim3(N_ / 16, B_), 512, 0, stream>>>(
      q, kT, vT, rel8, rlen, btab, Wp_tiled, bproj, out);
}

// Round 12
// 130.010 us; speedup vs baseline: 1.0842x; 1.0842x over previous
//
#include <hip/hip_runtime.h>
#include <hip/hip_bf16.h>

typedef __bf16 bf16;
typedef __bf16 bf16x2 __attribute__((ext_vector_type(2)));
typedef __bf16 bf16x4 __attribute__((ext_vector_type(4)));
typedef __bf16 bf16x8 __attribute__((ext_vector_type(8)));
typedef float f32x4 __attribute__((ext_vector_type(4)));
typedef int i32x4 __attribute__((ext_vector_type(4)));

#define B_ 8
#define N_ 1024
#define C_ 256
#define H_ 8
#define C3_ 768
#define SCALE 0.17677669529663689f  // 1/sqrt(32), pre-folded into q
#define FMAX 16.0f                  // fixed softmax max, pre-folded into ebtl

// ws layout:
//   Wp_tiled [8 kt][256 n][32 k]         131072 B  @ 393216
//   q  [8192][256] (pre-scaled by SCALE) 4 MiB     @ 524288
//   kT [b][h][1024 n][32 d]              4 MiB     @ 4718592
//   vT [b][c=h*32+d][1024 n']            4 MiB     @ 8912896
//   rel8 [b][i][j] int8                  8 MiB     @ 13107200
// vT perm (matches swapped-QK P fragment, k-slot = quad*8+e):
//   n' = (n&~31) | ((n&12)<<1) | (n&3) | (((n>>4)&1)<<2)

// ---------------------------------------------------------------------------
// Fused producer kernel (R10-frozen):
//   blocks 0..767    : 64x128 QKV gemm tiles, B staged directly from raw
//                      Wqkv (in-kernel transpose, XOR-chunk swizzle).
//   blocks 768..2815 : rel int32 -> int8 pack.
//   blocks 2816..3071: Wproj tiling.
// ---------------------------------------------------------------------------
__global__ __launch_bounds__(256) void gemm_qkv(
    const float* __restrict__ A, const float* __restrict__ Wqkv,
    const float* __restrict__ Wproj, const int* __restrict__ rel,
    bf16* __restrict__ q, bf16* __restrict__ kT, bf16* __restrict__ vT,
    bf16* __restrict__ Wp_tiled, unsigned char* __restrict__ rel8)
{
  __shared__ __align__(16) char sm[18432];

  int bb = blockIdx.x;
  int tid = threadIdx.x;

  if (bb >= 768) {
    if (bb < 2816) {
      // rel pack: 2048 blocks x 256 thr x 16 elems
      long p = ((long)(bb - 768) * 256 + tid) * 16;
      i32x4 a = *reinterpret_cast<const i32x4*>(rel + p);
      i32x4 b2 = *reinterpret_cast<const i32x4*>(rel + p + 4);
      i32x4 c = *reinterpret_cast<const i32x4*>(rel + p + 8);
      i32x4 d = *reinterpret_cast<const i32x4*>(rel + p + 12);
      unsigned o0 = (unsigned)a[0] | ((unsigned)a[1] << 8) | ((unsigned)a[2] << 16) | ((unsigned)a[3] << 24);
      unsigned o1 = (unsigned)b2[0] | ((unsigned)b2[1] << 8) | ((unsigned)b2[2] << 16) | ((unsigned)b2[3] << 24);
      unsigned o2 = (unsigned)c[0] | ((unsigned)c[1] << 8) | ((unsigned)c[2] << 16) | ((unsigned)c[3] << 24);
      unsigned o3 = (unsigned)d[0] | ((unsigned)d[1] << 8) | ((unsigned)d[2] << 16) | ((unsigned)d[3] << 24);
      i32x4 ov = {(int)o0, (int)o1, (int)o2, (int)o3};
      *reinterpret_cast<i32x4*>(rel8 + p) = ov;
    } else {
      int p = (bb - 2816) * 256 + tid;
      int kk = p & 31;
      int n = (p >> 5) & 255;
      int kt = p >> 13;
      Wp_tiled[p] = (bf16)Wproj[(kt * 32 + kk) * C_ + n];
    }
    return;
  }

  bf16 (*As)[40] = (bf16(*)[40])(void*)sm;            // [64][40]
  bf16 (*Bs)[40] = (bf16(*)[40])(void*)(sm + 5120);   // [128 n][40] (swizzled k)

  int wave = tid >> 6, lane = tid & 63, quad = lane >> 4, l16 = lane & 15;
  int x = bb & 127, y = bb >> 7;          // m-tile (64 rows), n-tile (128 cols)
  int m0 = x * 64, n0 = y * 128;
  int msub = (wave & 1) * 32, nsub = (wave >> 1) * 64;

  f32x4 acc[2][4] = {};

  int arow = tid >> 2, akc = (tid & 3) * 8;
  const float* aptr = A + (long)(m0 + arow) * C_ + akc;   // + kt*32

  int bk = tid >> 3, bns = (tid & 7) * 16;
  int bcp = (((bk >> 3) ^ (tid & 3)) << 3) + (bk & 7);
  const float* wq = Wqkv + (long)bk * C3_ + n0 + bns;     // + kt*32*C3_

  float4 a0 = *reinterpret_cast<const float4*>(aptr);
  float4 a1 = *reinterpret_cast<const float4*>(aptr + 4);
  float4 f0 = *reinterpret_cast<const float4*>(wq);
  float4 f1 = *reinterpret_cast<const float4*>(wq + 4);
  float4 f2 = *reinterpret_cast<const float4*>(wq + 8);
  float4 f3 = *reinterpret_cast<const float4*>(wq + 12);

  for (int kt = 0; kt < 8; ++kt) {
    __syncthreads();
    {
      bf16 at[8] = {(bf16)a0.x, (bf16)a0.y, (bf16)a0.z, (bf16)a0.w,
                    (bf16)a1.x, (bf16)a1.y, (bf16)a1.z, (bf16)a1.w};
      *reinterpret_cast<bf16x8*>(&As[arow][akc]) = *reinterpret_cast<bf16x8*>(at);
      float vv[16] = {f0.x, f0.y, f0.z, f0.w, f1.x, f1.y, f1.z, f1.w,
                      f2.x, f2.y, f2.z, f2.w, f3.x, f3.y, f3.z, f3.w};
#pragma unroll
      for (int i = 0; i < 16; ++i)
        Bs[bns + i][bcp] = (bf16)vv[i];
    }
    __syncthreads();

    if (kt < 7) {
      int kn = (kt + 1) * 32;
      a0 = *reinterpret_cast<const float4*>(aptr + kn);
      a1 = *reinterpret_cast<const float4*>(aptr + kn + 4);
      const float* wqn = wq + (long)kn * C3_;
      f0 = *reinterpret_cast<const float4*>(wqn);
      f1 = *reinterpret_cast<const float4*>(wqn + 4);
      f2 = *reinterpret_cast<const float4*>(wqn + 8);
      f3 = *reinterpret_cast<const float4*>(wqn + 12);
    }

    bf16x8 af[2], bfr[4];
#pragma unroll
    for (int mi = 0; mi < 2; ++mi)
      af[mi] = *reinterpret_cast<const bf16x8*>(&As[msub + mi * 16 + l16][quad * 8]);
#pragma unroll
    for (int ni = 0; ni < 4; ++ni)
      bfr[ni] = *reinterpret_cast<const bf16x8*>(
          &Bs[nsub + ni * 16 + l16][(quad ^ ni) << 3]);
#pragma unroll
    for (int mi = 0; mi < 2; ++mi)
#pragma unroll
      for (int ni = 0; ni < 4; ++ni)
        acc[mi][ni] = __builtin_amdgcn_mfma_f32_16x16x32_bf16(af[mi], bfr[ni], acc[mi][ni], 0, 0, 0);
  }

  __syncthreads();  // all frag reads done; reuse sm for epilogue staging

  if (y < 4) {
    float mul = (y < 2) ? SCALE : 1.0f;
    bf16 (*Ep)[136] = (bf16(*)[136])(void*)sm;
#pragma unroll
    for (int mi = 0; mi < 2; ++mi)
#pragma unroll
      for (int ni = 0; ni < 4; ++ni)
#pragma unroll
        for (int r = 0; r < 4; ++r)
          Ep[msub + mi * 16 + quad * 4 + r][nsub + ni * 16 + l16] =
              (bf16)(acc[mi][ni][r] * mul);
    __syncthreads();
    int row = tid >> 2, seg = tid & 3;
    i32x4 w0 = *reinterpret_cast<const i32x4*>(&Ep[row][seg * 32]);
    i32x4 w1 = *reinterpret_cast<const i32x4*>(&Ep[row][seg * 32 + 8]);
    i32x4 w2 = *reinterpret_cast<const i32x4*>(&Ep[row][seg * 32 + 16]);
    i32x4 w3 = *reinterpret_cast<const i32x4*>(&Ep[row][seg * 32 + 24]);
    bf16* dst;
    if (y < 2) {
      dst = q + (long)(m0 + row) * 256 + n0 + seg * 32;
    } else {
      int c = n0 - 256 + seg * 32;       // multiple of 32 -> exactly one h
      int h = c >> 5;
      int gr = m0 + row, b = gr >> 10, n = gr & 1023;
      dst = kT + (((long)(b * H_ + h)) * N_ + n) * 32;
    }
    *reinterpret_cast<i32x4*>(dst) = w0;
    *reinterpret_cast<i32x4*>(dst + 8) = w1;
    *reinterpret_cast<i32x4*>(dst + 16) = w2;
    *reinterpret_cast<i32x4*>(dst + 24) = w3;
  } else {
    bf16 (*Vls)[72] = (bf16(*)[72])(void*)sm;
#pragma unroll
    for (int mi = 0; mi < 2; ++mi)
#pragma unroll
      for (int ni = 0; ni < 4; ++ni)
#pragma unroll
        for (int r = 0; r < 4; ++r) {
          int nn = msub + mi * 16 + quad * 4 + r;   // 0..63
          int np = (nn & ~31) | ((nn & 12) << 1) | (nn & 3) | (((nn >> 4) & 1) << 2);
          Vls[nsub + ni * 16 + l16][np] = (bf16)acc[mi][ni][r];
        }
    __syncthreads();
    int c = tid >> 1, nseg = (tid & 1) * 32;
    i32x4 w0 = *reinterpret_cast<const i32x4*>(&Vls[c][nseg]);
    i32x4 w1 = *reinterpret_cast<const i32x4*>(&Vls[c][nseg + 8]);
    i32x4 w2 = *reinterpret_cast<const i32x4*>(&Vls[c][nseg + 16]);
    i32x4 w3 = *reinterpret_cast<const i32x4*>(&Vls[c][nseg + 24]);
    int gb = m0 >> 10, mn = m0 & 1023;
    bf16* dst = vT + ((long)(gb * C_ + (n0 - 512) + c)) * N_ + mn + nseg;
    *reinterpret_cast<i32x4*>(dst) = w0;
    *reinterpret_cast<i32x4*>(dst + 8) = w1;
    *reinterpret_cast<i32x4*>(dst + 16) = w2;
    *reinterpret_cast<i32x4*>(dst + 24) = w3;
  }
}

// ---------------------------------------------------------------------------
// Flash attention + fused projection — QBLK=32: each block owns 32 q-rows
// (grid 256 = 8 XCDs x 32). Same K/V DMA per tile now feeds TWO Q-fragments
// (2x compute density per wave) and total K/V L2 traffic HALVES (each batch
// streamed by 32 blocks instead of 64). rel8 staged as ONE GLD16/tile (1KB =
// 32 rows x 32B, linear lane*16). 5 DMAs/tile, vmcnt(5), same replay-proven
// WAR schedule as R11 (double-buffered KV + rel, order-proof full-drain
// prologue). LDS 82432 -> 1 block/CU; R8-vs-R11 proved occupancy-parity.
// ---------------------------------------------------------------------------
__global__ __launch_bounds__(512) void flash_attn(
    const bf16* __restrict__ q, const bf16* __restrict__ kT,
    const bf16* __restrict__ vT, const unsigned char* __restrict__ rel8,
    const int* __restrict__ rel_len, const float* __restrict__ btab,
    const bf16* __restrict__ Wp_tiled, const float* __restrict__ bias,
    float* __restrict__ out)
{
  __shared__ __align__(16) char smem[82432];
  char* const KB0 = smem;            // [2][8][2048]
  char* const VB0 = smem + 32768;    // [2][8][2048]
  char* const RB0 = smem + 65536;    // [2][8][1024]  (32 rows x 32B per h)
  float* const ebtl = (float*)(smem + 81920);  // [8][16]

  int tid = threadIdx.x;
  int h = tid >> 6, lane = tid & 63, quad = lane >> 4, l16 = lane & 15;

  // bijective XCD swizzle (256 blocks = 8 XCDs x 32): XCD k -> batch k.
  int wg = blockIdx.y * 32 + blockIdx.x;
  int swz = (wg & 7) * 32 + (wg >> 3);
  int b = swz >> 5, i0 = (swz & 31) * 32;
  long bN = (long)b * N_;

  int mask_len = (int)((float)rel_len[b] * 0.5f);
  if (tid < 80) {
    int t = tid >> 3, hh = tid & 7;
    ebtl[hh * 16 + t] = __expf(btab[t * H_ + hh] + (t > mask_len ? -100.f : 0.f) - FMAX);
  }

  // Q as B-fragment: col = q-row (l16 / 16+l16), k = d (quad*8+e)
  bf16x8 qfA = *reinterpret_cast<const bf16x8*>(
      q + (bN + i0 + l16) * 256 + h * 32 + quad * 8);
  bf16x8 qfB = *reinterpret_cast<const bf16x8*>(
      q + (bN + i0 + 16 + l16) * 256 + h * 32 + quad * 8);

  // ebtl visible + prologue VMEM drained so loop vmcnt counts only DMAs.
  __syncthreads();

  // ---- per-lane DMA source offsets (16B-slot swizzle pre-applied) ----
  int l = lane;
  int sxc = (((l & 3) ^ ((l >> 3) & 3)) << 4);
  int kc0 = (l >> 2) * 64 + sxc;                  // K: row l>>2, 2nd GLD +1024
  int vc0 = (h * 32 + (l >> 2)) * 2048 + sxc;     // V: chan h*32+(l>>2), 2nd +32768
  int rc0 = (l >> 1) * 1024 + (l & 1) * 16;       // rel8: row l>>1, half l&1

  const char* kTb = (const char*)kT + ((long)(b * 8 + h) << 16);  // +t*2048
  const char* vTb = (const char*)vT + (long)b * 524288;           // +t*64
  const char* rb8 = (const char*)rel8 + (bN + i0) * 1024;         // +t*32

  // ---- LDS read offsets ----
  int swq = ((quad ^ ((l16 >> 1) & 3)) << 4);
  int kr = h * 2048 + l16 * 64 + swq;       // K/V: row l16 (+1024: row 16+l16)
  int rr = h * 1024 + l16 * 32 + quad * 4;  // rel8: row l16 (+512: row 16+l16)

#define KB(i) (KB0 + (i) * 16384)
#define VB(i) (VB0 + (i) * 16384)
#define RB(i) (RB0 + (i) * 8192)

#define GLD16(G, L) __builtin_amdgcn_global_load_lds(                         \
    (const __attribute__((address_space(1))) void*)(G),                       \
    (__attribute__((address_space(3))) void*)(L), 16, 0, 0)

  // 16-wide gather: [0..7] = frag A (rows l16; j 4q+e, 16+4q+e),
  //                 [8..15] = frag B (rows 16+l16).
#define GATH(G, RV0, RV1, RV2, RV3) do {                                      \
    _Pragma("unroll")                                                         \
    for (int e = 0; e < 4; ++e) {                                             \
      G[e]      = ebtl[h * 16 + (int)((RV0 >> (8 * e)) & 255u)];              \
      G[4 + e]  = ebtl[h * 16 + (int)((RV1 >> (8 * e)) & 255u)];              \
      G[8 + e]  = ebtl[h * 16 + (int)((RV2 >> (8 * e)) & 255u)];              \
      G[12 + e] = ebtl[h * 16 + (int)((RV3 >> (8 * e)) & 255u)];              \
    }                                                                         \
  } while (0)

#define COMP(K0, K1, V0, V1, G) do {                                          \
    f32x4 z = {};                                                             \
    f32x4 s0A = __builtin_amdgcn_mfma_f32_16x16x32_bf16(K0, qfA, z, 0, 0, 0); \
    f32x4 s1A = __builtin_amdgcn_mfma_f32_16x16x32_bf16(K1, qfA, z, 0, 0, 0); \
    f32x4 s0B = __builtin_amdgcn_mfma_f32_16x16x32_bf16(K0, qfB, z, 0, 0, 0); \
    f32x4 s1B = __builtin_amdgcn_mfma_f32_16x16x32_bf16(K1, qfB, z, 0, 0, 0); \
    bf16x8 paA, paB;                                                          \
    _Pragma("unroll")                                                         \
    for (int e = 0; e < 4; ++e) {                                             \
      float pA0 = __expf(s0A[e]) * G[e];                                      \
      float pA1 = __expf(s1A[e]) * G[4 + e];                                  \
      float pB0 = __expf(s0B[e]) * G[8 + e];                                  \
      float pB1 = __expf(s1B[e]) * G[12 + e];                                 \
      l_accA += pA0 + pA1;                                                    \
      l_accB += pB0 + pB1;                                                    \
      paA[e] = (bf16)pA0; paA[4 + e] = (bf16)pA1;                             \
      paB[e] = (bf16)pB0; paB[4 + e] = (bf16)pB1;                             \
    }                                                                         \
    oA0 = __builtin_amdgcn_mfma_f32_16x16x32_bf16(paA, V0, oA0, 0, 0, 0);     \
    oA1 = __builtin_amdgcn_mfma_f32_16x16x32_bf16(paA, V1, oA1, 0, 0, 0);     \
    oB0 = __builtin_amdgcn_mfma_f32_16x16x32_bf16(paB, V0, oB0, 0, 0, 0);     \
    oB1 = __builtin_amdgcn_mfma_f32_16x16x32_bf16(paB, V1, oB1, 0, 0, 0);     \
  } while (0)

// Tile T (KVR=T&1, KVW=(T+1)&1): issue KV(T+1)->KB/VB(KVW) [4] and
// rel8(T+2)->RB(KVR) [1]; vmcnt(5) leaves only this tile's 5 outstanding ->
// KV(T) and rel8(T+1) (issued at T-1) arrived; read KV(T) from KVR, read-
// ahead rel8(T+1) from RB(KVW); gather GN for T+1; compute T with GC.
// WAR on RB(KVR): read at T-1 precedes this issue in program order (R11-
// replay-proven pattern). No barriers.
#define TILE(T_, KVR, KVW, GC, GN) do {                                       \
    int tn_ = ((T_) + 1) & 31, tr_ = ((T_) + 2) & 31;                         \
    GLD16(kTb + tn_ * 2048 + kc0,        KB(KVW) + h * 2048);                 \
    GLD16(kTb + tn_ * 2048 + kc0 + 1024, KB(KVW) + h * 2048 + 1024);          \
    GLD16(vTb + tn_ * 64 + vc0,          VB(KVW) + h * 2048);                 \
    GLD16(vTb + tn_ * 64 + vc0 + 32768,  VB(KVW) + h * 2048 + 1024);          \
    GLD16(rb8 + tr_ * 32 + rc0,          RB(KVR) + h * 1024);                 \
    asm volatile("s_waitcnt vmcnt(5)" ::: "memory");                          \
    bf16x8 kf0 = *(const bf16x8*)(KB(KVR) + kr);                              \
    bf16x8 kf1 = *(const bf16x8*)(KB(KVR) + kr + 1024);                       \
    bf16x8 vf0 = *(const bf16x8*)(VB(KVR) + kr);                              \
    bf16x8 vf1 = *(const bf16x8*)(VB(KVR) + kr + 1024);                       \
    unsigned rv0 = *(const unsigned*)(RB(KVW) + rr);                          \
    unsigned rv1 = *(const unsigned*)(RB(KVW) + rr + 16);                     \
    unsigned rv2 = *(const unsigned*)(RB(KVW) + rr + 512);                    \
    unsigned rv3 = *(const unsigned*)(RB(KVW) + rr + 528);                    \
    GATH(GN, rv0, rv1, rv2, rv3);                                             \
    COMP(kf0, kf1, vf0, vf1, GC);                                             \
  } while (0)

  f32x4 oA0 = {}, oA1 = {}, oB0 = {}, oB1 = {};
  float l_accA = 0.f, l_accB = 0.f;
  float gA[16], gB[16];

  // ---- prologue: KV(0)->buf0; rel8(0)->RB(0), rel8(1)->RB(1); full drain
  // (order-proof); gather gA for tile 0.
  GLD16(kTb + kc0,        KB(0) + h * 2048);
  GLD16(kTb + kc0 + 1024, KB(0) + h * 2048 + 1024);
  GLD16(vTb + vc0,          VB(0) + h * 2048);
  GLD16(vTb + vc0 + 32768,  VB(0) + h * 2048 + 1024);
  GLD16(rb8 + rc0,        RB(0) + h * 1024);
  GLD16(rb8 + 32 + rc0,   RB(1) + h * 1024);
  asm volatile("s_waitcnt vmcnt(0)" ::: "memory");
  {
    unsigned rv0 = *(const unsigned*)(RB(0) + rr);
    unsigned rv1 = *(const unsigned*)(RB(0) + rr + 16);
    unsigned rv2 = *(const unsigned*)(RB(0) + rr + 512);
    unsigned rv3 = *(const unsigned*)(RB(0) + rr + 528);
    GATH(gA, rv0, rv1, rv2, rv3);
  }
  // t=0 writes rel8(2) into RB(0): gA gathered above, before that issue. ✓

#pragma unroll 1
  for (int t = 0; t < 32; t += 2) {
    TILE(t + 0, 0, 1, gA, gB);
    TILE(t + 1, 1, 0, gB, gA);
  }
#undef TILE
#undef COMP
#undef GATH
#undef GLD16
#undef KB
#undef VB
#undef RB

  // drain wrapped tail DMAs before aliasing smem as attL
  asm volatile("s_waitcnt vmcnt(0)" ::: "memory");
  __syncthreads();

  // row sums: l_accA covers q-row l16, l_accB covers q-row 16+l16;
  // reduce across the quad bits (lanes ^16, ^32).
  float lsumA = l_accA;
  lsumA += __shfl_xor(lsumA, 16);
  lsumA += __shfl_xor(lsumA, 32);
  float invA = 1.f / lsumA;
  float lsumB = l_accB;
  lsumB += __shfl_xor(lsumB, 16);
  lsumB += __shfl_xor(lsumB, 32);
  float invB = 1.f / lsumB;

  bf16 (*attL)[264] = (bf16(*)[264])(void*)smem;   // [32][264]
#pragma unroll
  for (int r = 0; r < 4; ++r) {
    float invAr = __shfl(invA, quad * 4 + r);   // row quad*4+r
    float invBr = __shfl(invB, quad * 4 + r);   // row 16+quad*4+r
    attL[quad * 4 + r][h * 32 + l16] = (bf16)(oA0[r] * invAr);
    attL[quad * 4 + r][h * 32 + 16 + l16] = (bf16)(oA1[r] * invAr);
    attL[16 + quad * 4 + r][h * 32 + l16] = (bf16)(oB0[r] * invBr);
    attL[16 + quad * 4 + r][h * 32 + 16 + l16] = (bf16)(oB1[r] * invBr);
  }
  __syncthreads();

  // fused projection: wave h computes out[32 rows][h*32 .. h*32+31]
  f32x4 pA[2] = {}, pB[2] = {};
  const bf16* wp = Wp_tiled + ((h * 32 + l16) * 32 + quad * 8);  // + kt*8192, +512 for ni=1
#pragma unroll
  for (int kt = 0; kt < 8; ++kt) {
    bf16x8 af0 = *reinterpret_cast<const bf16x8*>(&attL[l16][kt * 32 + quad * 8]);
    bf16x8 af1 = *reinterpret_cast<const bf16x8*>(&attL[16 + l16][kt * 32 + quad * 8]);
    bf16x8 b0 = *reinterpret_cast<const bf16x8*>(wp + kt * 8192);
    bf16x8 b1 = *reinterpret_cast<const bf16x8*>(wp + kt * 8192 + 512);
    pA[0] = __builtin_amdgcn_mfma_f32_16x16x32_bf16(af0, b0, pA[0], 0, 0, 0);
    pA[1] = __builtin_amdgcn_mfma_f32_16x16x32_bf16(af0, b1, pA[1], 0, 0, 0);
    pB[0] = __builtin_amdgcn_mfma_f32_16x16x32_bf16(af1, b0, pB[0], 0, 0, 0);
    pB[1] = __builtin_amdgcn_mfma_f32_16x16x32_bf16(af1, b1, pB[1], 0, 0, 0);
  }
  float bi0 = bias[h * 32 + l16];
  float bi1 = bias[h * 32 + 16 + l16];
#pragma unroll
  for (int r = 0; r < 4; ++r) {
    long rowoffA = (bN + i0 + quad * 4 + r) * C_ + h * 32;
    long rowoffB = (bN + i0 + 16 + quad * 4 + r) * C_ + h * 32;
    out[rowoffA + l16] = pA[0][r] + bi0;
    out[rowoffA + 16 + l16] = pA[1][r] + bi1;
    out[rowoffB + l16] = pB[0][r] + bi0;
    out[rowoffB + 16 + l16] = pB[1][r] + bi1;
  }
}

// ---------------------------------------------------------------------------
extern "C" void kernel_launch(void* const* d_in, const int* in_sizes, int n_in,
                              void* d_out, int out_size, void* d_ws, size_t ws_size,
                              hipStream_t stream) {
  const float* X     = (const float*)d_in[0];   // att_embedding [8,1024,256] fp32
  const int*   rel   = (const int*)d_in[1];     // relation_position [8,1024,1024]
  const int*   rlen  = (const int*)d_in[2];     // rel_len [8]
  const float* Wqkv  = (const float*)d_in[3];   // [256,768] fp32
  const float* Wproj = (const float*)d_in[4];   // [256,256] fp32
  const float* bproj = (const float*)d_in[5];   // [256] fp32
  const float* btab  = (const float*)d_in[6];   // [10,8] fp32
  float* out = (float*)d_out;                   // [8,1024,256] fp32

  char* ws = (char*)d_ws;
  bf16* Wp_tiled = (bf16*)(ws + 393216);                 // 131072 B
  bf16* q  = (bf16*)(ws + 524288);                       // 4 MiB
  bf16* kT = (bf16*)(ws + 524288 + 4194304);             // 4 MiB
  bf16* vT = (bf16*)(ws + 524288 + 2 * 4194304);         // 4 MiB
  unsigned char* rel8 = (unsigned char*)(ws + 13107200); // 8 MiB

  gemm_qkv<<<dim3(3072), 256, 0, stream>>>(X, Wqkv, Wproj, rel,
                                           q, kT, vT, Wp_tiled, rel8);
  flash_attn<<<dim3(32, B_), 512, 0, stream>>>(
      q, kT, vT, rel8, rlen, btab, Wp_tiled, bproj, out);
}